// Round 16
// baseline (351.683 us; speedup 1.0000x reference)
//
#include <hip/hip_runtime.h>
#include <math.h>
#include <stdint.h>

#define SEQ 4096
#define DIM 1024
#define NB  4
#define TRI  528              // 128-tile triangular count (sp indexing)

typedef __attribute__((ext_vector_type(8))) __bf16 bf16x8;
typedef __attribute__((ext_vector_type(4))) float  f32x4;
typedef __attribute__((ext_vector_type(4))) float  floatx4;
typedef __attribute__((ext_vector_type(8))) unsigned short ushortx8;
typedef __attribute__((ext_vector_type(4))) unsigned short ushortx4;

// panel layout for P: per batch, 16 panels; panel T = 256 rows x 256(T+1) cols
// elem offset of panel T: 32768*T*(T+1); batch stride = 8912896 elems
#define PANEL_OFF(T)  ((size_t)32768 * (T) * ((T) + 1))
#define PBATCH        ((size_t)8912896)

__device__ __forceinline__ unsigned short f2bf(float f){
  union { float f; unsigned int u; } c; c.f = f;
  unsigned int u = c.u;
  return (unsigned short)((u + 0x7fffu + ((u >> 16) & 1u)) >> 16);
}

__device__ __forceinline__ f32x4 mfma16(bf16x8 a, bf16x8 b, f32x4 c){
  return __builtin_amdgcn_mfma_f32_16x16x32_bf16(a, b, c, 0, 0, 0);
}

__device__ __forceinline__ void g2l16(void* lds, const void* g){
  __builtin_amdgcn_global_load_lds(
      (const __attribute__((address_space(1))) unsigned int*)g,
      (__attribute__((address_space(3))) unsigned int*)lds, 16, 0, 0);
}

#define WAITVM0 asm volatile("s_waitcnt vmcnt(0)" ::: "memory")

#define BARRAW() do { asm volatile("" ::: "memory"); \
  __builtin_amdgcn_s_barrier(); asm volatile("" ::: "memory"); } while (0)
#define VM6_BAR() do { asm volatile("s_waitcnt vmcnt(6)" ::: "memory"); \
  __builtin_amdgcn_s_barrier(); asm volatile("" ::: "memory"); } while (0)
#define LGKM0() do { asm volatile("s_waitcnt lgkmcnt(0)" ::: "memory"); \
  __builtin_amdgcn_sched_barrier(0); } while (0)

#define SWZB(r) (((r) & 7) << 4)

// stage one 128x64 bf16 tile (sp kernel; linear LDS dest, swizzled source)
#define STAGE_AB(Aptr, Astr, Bptr, Bstr) do { \
  _Pragma("unroll") \
  for (int _c = 0; _c < 4; ++_c){ \
    int _id  = _c * 256 + t; \
    int _row = _id >> 3; \
    int _sw  = ((_id & 7) * 16) ^ SWZB(_row); \
    g2l16((char*)As + (size_t)_id * 16, \
          (const char*)(Aptr) + (size_t)_row * (Astr) + _sw); \
    g2l16((char*)Bs + (size_t)_id * 16, \
          (const char*)(Bptr) + (size_t)_row * (Bstr) + _sw); \
  } \
} while (0)

// 128x128-tile MFMA step (sp kernel)
#define COMPUTE128S() do { \
  _Pragma("unroll") \
  for (int _ks = 0; _ks < 2; ++_ks){ \
    bf16x8 _af[4], _bf[4]; \
    _Pragma("unroll") \
    for (int _i = 0; _i < 4; ++_i){ \
      int _ra = wr + _i*16 + lr; \
      int _rb = wc + _i*16 + lr; \
      _af[_i] = *(const bf16x8*)((const char*)As + (size_t)_ra * 128 \
                                 + ((_ks*64 + lk16) ^ SWZB(_ra))); \
      _bf[_i] = *(const bf16x8*)((const char*)Bs + (size_t)_rb * 128 \
                                 + ((_ks*64 + lk16) ^ SWZB(_rb))); \
    } \
    __builtin_amdgcn_s_setprio(1); \
    _Pragma("unroll") \
    for (int _i = 0; _i < 4; ++_i) \
      _Pragma("unroll") \
      for (int _j = 0; _j < 4; ++_j) \
        acc[_i][_j] = mfma16(_af[_i], _bf[_j], acc[_i][_j]); \
    __builtin_amdgcn_s_setprio(0); \
  } \
} while (0)

// ================= 8-phase 256x256 GEMM core (qkv only; r14/r15-measured) ==
#define HT_STAGE(DST, SRC, KT, KH) do {                                   \
  g2l16((DST) + (size_t)t * 16,         (SRC) + so0 + (KT)*128 + (KH)*64);\
  g2l16((DST) + (size_t)(512 + t) * 16, (SRC) + so1 + (KT)*128 + (KH)*64);\
} while (0)

#define MFMA16X(NH) do {                                                  \
  __builtin_amdgcn_s_setprio(1);                                          \
  _Pragma("unroll")                                                       \
  for (int i = 0; i < 8; ++i){                                            \
    acc[i][(NH)*2]     = mfma16(af[i], b0, acc[i][(NH)*2]);               \
    acc[i][(NH)*2 + 1] = mfma16(af[i], b1, acc[i][(NH)*2 + 1]);           \
  }                                                                       \
  __builtin_amdgcn_s_setprio(0);                                          \
} while (0)

#define CORE8PH(ASRC, BSRC)                                               \
  f32x4 acc[8][4];                                                        \
  _Pragma("unroll")                                                       \
  for (int i = 0; i < 8; ++i)                                             \
    _Pragma("unroll")                                                     \
    for (int j = 0; j < 4; ++j) acc[i][j] = (f32x4)0.0f;                  \
  int aoff[8], boff[4];                                                   \
  _Pragma("unroll")                                                       \
  for (int i = 0; i < 8; ++i){                                            \
    int rr = wm*128 + i*16 + lr;                                          \
    aoff[i] = (rr>>1)*128 + ((((rr&1)*4 + lk) ^ ((rr>>1)&7))*16);         \
  }                                                                       \
  _Pragma("unroll")                                                       \
  for (int j = 0; j < 4; ++j){                                            \
    int rr = wn*64 + j*16 + lr;                                           \
    boff[j] = 32768 + (rr>>1)*128 + ((((rr&1)*4 + lk) ^ ((rr>>1)&7))*16); \
  }                                                                       \
  int so0, so1;                                                           \
  {                                                                       \
    int L0 = t >> 3,        sx0 = (t & 7) ^ (L0 & 7);                     \
    so0 = (2*L0 + (sx0>>2))*2048 + (sx0&3)*16;                            \
    int L1 = (512+t) >> 3,  sx1 = ((512+t) & 7) ^ (L1 & 7);               \
    so1 = (2*L1 + (sx1>>2))*2048 + (sx1&3)*16;                            \
  }                                                                       \
  HT_STAGE(ldsb,          ASRC, 0, 0);                                    \
  HT_STAGE(ldsb + 32768,  BSRC, 0, 0);                                    \
  HT_STAGE(ldsb + 16384,  ASRC, 0, 1);                                    \
  HT_STAGE(ldsb + 49152,  BSRC, 0, 1);                                    \
  HT_STAGE(ldsb + 65536,  ASRC, 1, 0);                                    \
  HT_STAGE(ldsb + 98304,  BSRC, 1, 0);                                    \
  asm volatile("s_waitcnt vmcnt(8)" ::: "memory");                        \
  __builtin_amdgcn_s_barrier();                                           \
  asm volatile("" ::: "memory");                                          \
  for (int U = 0; U < 15; ++U){                                           \
    char* bufc = ldsb + (size_t)(U & 1) * 65536;                          \
    char* bufn = ldsb + (size_t)((U + 1) & 1) * 65536;                    \
    bf16x8 af[8], b0, b1;                                                 \
    _Pragma("unroll")                                                     \
    for (int i = 0; i < 8; ++i) af[i] = *(const bf16x8*)(bufc + aoff[i]); \
    b0 = *(const bf16x8*)(bufc + boff[0]);                                \
    b1 = *(const bf16x8*)(bufc + boff[1]);                                \
    HT_STAGE(bufn + 16384, ASRC, U + 1, 1);                               \
    BARRAW(); LGKM0();                                                    \
    MFMA16X(0);                                                           \
    BARRAW();                                                             \
    b0 = *(const bf16x8*)(bufc + boff[2]);                                \
    b1 = *(const bf16x8*)(bufc + boff[3]);                                \
    HT_STAGE(bufn + 49152, BSRC, U + 1, 1);                               \
    BARRAW(); LGKM0();                                                    \
    MFMA16X(1);                                                           \
    VM6_BAR();                                                            \
    _Pragma("unroll")                                                     \
    for (int i = 0; i < 8; ++i)                                           \
      af[i] = *(const bf16x8*)(bufc + 16384 + aoff[i]);                   \
    b0 = *(const bf16x8*)(bufc + boff[0] + 16384);                        \
    b1 = *(const bf16x8*)(bufc + boff[1] + 16384);                        \
    if (U < 14) HT_STAGE(bufc, ASRC, U + 2, 0);                           \
    BARRAW(); LGKM0();                                                    \
    MFMA16X(0);                                                           \
    BARRAW();                                                             \
    b0 = *(const bf16x8*)(bufc + boff[2] + 16384);                        \
    b1 = *(const bf16x8*)(bufc + boff[3] + 16384);                        \
    if (U < 14) HT_STAGE(bufc + 32768, BSRC, U + 2, 0);                   \
    BARRAW(); LGKM0();                                                    \
    MFMA16X(1);                                                           \
    VM6_BAR();                                                            \
  }                                                                       \
  {                                                                       \
    char* bufc = ldsb + 65536;                                            \
    WAITVM0;                                                              \
    __builtin_amdgcn_s_barrier();                                         \
    asm volatile("" ::: "memory");                                        \
    _Pragma("unroll")                                                     \
    for (int ks = 0; ks < 2; ++ks){                                       \
      bf16x8 af[8], b0, b1;                                               \
      _Pragma("unroll")                                                   \
      for (int i = 0; i < 8; ++i)                                         \
        af[i] = *(const bf16x8*)(bufc + ks*16384 + aoff[i]);              \
      _Pragma("unroll")                                                   \
      for (int j = 0; j < 4; j += 2){                                     \
        b0 = *(const bf16x8*)(bufc + boff[j]   + ks*16384);               \
        b1 = *(const bf16x8*)(bufc + boff[j+1] + ks*16384);               \
        _Pragma("unroll")                                                 \
        for (int i = 0; i < 8; ++i){                                      \
          acc[i][j]   = mfma16(af[i], b0, acc[i][j]);                     \
          acc[i][j+1] = mfma16(af[i], b1, acc[i][j+1]);                   \
        }                                                                 \
      }                                                                   \
    }                                                                     \
  }

// ---------------- fp32 -> bf16 conversion (all 4 inputs fused) ------------
__global__ void cvt_all(const float* __restrict__ emb,
                        const float* __restrict__ Wq,
                        const float* __restrict__ Wk,
                        const float* __restrict__ Wv,
                        unsigned short* __restrict__ EB,
                        unsigned short* __restrict__ WB){
  int i = blockIdx.x * blockDim.x + threadIdx.x;
  const float* src;
  unsigned short* dst;
  int idx;
  if (i < 4194304){ src = emb; dst = EB; idx = i; }
  else {
    int j = i - 4194304;
    int w = j >> 18;           // 0..2
    idx = j & 262143;
    src = w == 0 ? Wq : (w == 1 ? Wk : Wv);
    dst = WB + (size_t)w * 1048576;
  }
  floatx4 v = *((const floatx4*)src + idx);
  ushortx4 o;
  o[0] = f2bf(v[0]); o[1] = f2bf(v[1]); o[2] = f2bf(v[2]); o[3] = f2bf(v[3]);
  *((ushortx4*)dst + idx) = o;
}

// ---------------- zero panel holes: panel T rows 0..127, last 128 cols ----
__global__ __launch_bounds__(256) void zero_holes(unsigned short* __restrict__ Sp){
  const int T = blockIdx.x;
  const int b = blockIdx.y;
  unsigned short* Pp = Sp + b * PBATCH + PANEL_OFF(T);
  const int W = 256 * (T + 1);
  const int c0 = (2 * T + 1) * 128;
  const int t = threadIdx.x;
  #pragma unroll
  for (int k = 0; k < 8; ++k){
    int v = k * 256 + t;          // 0..2047
    int row = v >> 4;
    int col = (v & 15) * 8;
    *(ushortx8*)&Pp[(size_t)row * W + c0 + col] = (ushortx8)0;
  }
}

// ---------------- QKV projection GEMM: 256^2 8-phase + XCD remap (r15) ----
__global__ __launch_bounds__(512, 1) void gemm_qkv(
    const unsigned short* __restrict__ E,
    const unsigned short* __restrict__ W3,
    unsigned short* __restrict__ Qd,
    unsigned short* __restrict__ Kd,
    unsigned short* __restrict__ Vd)
{
  __shared__ char ldsbuf[131072];
  char* ldsb = ldsbuf;

  const int bid = blockIdx.x;          // 0..767
  const int xcd = bid & 7;
  const int s   = bid >> 3;            // 0..95
  const int ml  = s / 12;
  const int r12 = s - ml * 12;
  const int mt  = xcd * 8 + ml;        // 0..63
  const int nt  = r12 & 3;             // 0..3
  const int z   = r12 >> 2;            // 0..2

  const int m0 = mt * 256;
  const int n0 = nt * 256;
  const unsigned short* W = W3 + (size_t)z * (DIM * (size_t)DIM);
  unsigned short* dst = z == 0 ? Qd : (z == 1 ? Kd : Vd);

  const int t  = threadIdx.x;
  const int w  = t >> 6;
  const int l  = t & 63;
  const int lr = l & 15;
  const int lk = l >> 4;
  const int wm = w >> 2;
  const int wn = w & 3;

  const char* Asl = (const char*)E + (size_t)m0 * 2048;
  const char* Bsl = (const char*)W + (size_t)n0 * 2048;

  CORE8PH(Asl, Bsl);

  #pragma unroll
  for (int i = 0; i < 8; ++i)
    #pragma unroll
    for (int j = 0; j < 4; ++j)
      #pragma unroll
      for (int r = 0; r < 4; ++r){
        int row = wm * 128 + i * 16 + lk * 4 + r;
        int col = wn * 64 + j * 16 + lr;
        dst[(size_t)(m0 + row) * DIM + n0 + col] = f2bf(acc[i][j][r]);
      }
}

// ---------------- V transpose ----------------
__global__ __launch_bounds__(256) void transpose_v(
    const unsigned short* __restrict__ V, unsigned short* __restrict__ VT)
{
  __shared__ unsigned short T[64][72];
  const int b  = blockIdx.z;
  const int s0 = blockIdx.x * 64;
  const int a0 = blockIdx.y * 64;
  const unsigned short* Vb = V + (size_t)b * SEQ * DIM;
  unsigned short* VTb = VT + (size_t)b * DIM * SEQ;
  const int t = threadIdx.x;
  const int r = t >> 3, cg = t & 7;
  #pragma unroll
  for (int p = 0; p < 2; ++p){
    int row = r + p * 32;
    ushortx8 v = *(const ushortx8*)(Vb + (size_t)(s0 + row) * DIM + a0 + cg*8);
    *(ushortx8*)&T[row][cg*8] = v;
  }
  __syncthreads();
  #pragma unroll
  for (int p = 0; p < 2; ++p){
    int ar = r + p * 32;
    ushortx8 o;
    #pragma unroll
    for (int j = 0; j < 8; ++j) o[j] = T[cg*8 + j][ar];
    *(ushortx8*)(VTb + (size_t)(a0 + ar) * SEQ + s0 + cg*8) = o;
  }
}

// ---------------- S/P GEMM: r15 form; writes P into panel layout ----------
__global__ __launch_bounds__(256, 2) void sp_gemm(
    const unsigned short* __restrict__ Q,
    const unsigned short* __restrict__ K,
    unsigned short* __restrict__ Sp,
    float* __restrict__ lrow)
{
  const int orig = blockIdx.x;         // 0..527
  const int p    = (orig & 7) * 66 + (orig >> 3);
  const int b    = blockIdx.y;

  int ti = (int)((__builtin_sqrtf(8.0f * (float)p + 1.0f) - 1.0f) * 0.5f);
  while ((ti + 1) * (ti + 2) / 2 <= p) ++ti;
  while (ti * (ti + 1) / 2 > p) --ti;
  const int tj = p - ti * (ti + 1) / 2;

  __shared__ unsigned short As[128 * 64];
  __shared__ unsigned short Bs[128 * 64];

  const int t  = threadIdx.x;
  const int m0 = ti * 128;
  const int n0 = tj * 128;

  const int l  = t & 63;
  const int w  = t >> 6;
  const int lr = l & 15;
  const int lk = l >> 4;
  const int lk16 = lk * 16;
  const int wr = (w >> 1) * 64;
  const int wc = (w & 1) * 64;

  const char* Abase = (const char*)(Q + (size_t)b * SEQ * DIM) + (size_t)m0 * 2048;
  const char* Bbase = (const char*)(K + (size_t)b * SEQ * DIM) + (size_t)n0 * 2048;

  f32x4 acc[4][4];
  #pragma unroll
  for (int i = 0; i < 4; ++i)
    #pragma unroll
    for (int j = 0; j < 4; ++j) acc[i][j] = (f32x4)0.0f;

  for (int kt = 0; kt < DIM / 64; ++kt){
    STAGE_AB(Abase + kt * 128, 2048, Bbase + kt * 128, 2048);
    WAITVM0;
    __syncthreads();
    COMPUTE128S();
    __syncthreads();
  }

  // epilogue: P = exp(scale*acc) masked; write into panel layout; row sums
  const float scale = 0.03125f;  // 1/sqrt(1024)
  const int Tp = ti >> 1;
  const int Wp = 256 * (Tp + 1);
  const int rowbase = (ti & 1) * 128;
  unsigned short* Pp = Sp + (size_t)b * PBATCH + PANEL_OFF(Tp);
  float* lb = lrow + (size_t)b * SEQ + m0;

  #pragma unroll
  for (int i = 0; i < 4; ++i){
    float rs[4] = {0.f, 0.f, 0.f, 0.f};
    #pragma unroll
    for (int j = 0; j < 4; ++j){
      #pragma unroll
      for (int r = 0; r < 4; ++r){
        int row = wr + i*16 + lk*4 + r;
        int col = wc + j*16 + lr;
        float pv = 0.0f;
        if (n0 + col <= m0 + row) pv = __expf(acc[i][j][r] * scale);
        rs[r] += pv;
        Pp[(size_t)(rowbase + row) * Wp + n0 + col] = f2bf(pv);
      }
    }
    #pragma unroll
    for (int r = 0; r < 4; ++r){
      float v = rs[r];
      v += __shfl_xor(v, 1, 64);
      v += __shfl_xor(v, 2, 64);
      v += __shfl_xor(v, 4, 64);
      v += __shfl_xor(v, 8, 64);
      if (lr == 0)
        atomicAdd(&lb[wr + i*16 + lk*4 + r], v);
    }
  }
}

// ---------------- PV GEMM v2: M=256 panel tiles, N=128; O = (P V)/l --------
// grid (64, NB), 512 thr (8 waves: wm=w>>1 row-quarter, wn=w&1 col-half).
// f chunked: xcd = f&7 -> pair = xcd (P-panels L2-shared), nx = f>>3.
// Per block: panels (15-pair) then (pair); ksteps 4(T+1) each (68 total).
__global__ __launch_bounds__(512, 1) void pv_gemm(
    const unsigned short* __restrict__ Sp,
    const unsigned short* __restrict__ VT,
    const float* __restrict__ lrow,
    float* __restrict__ out)
{
  __shared__ unsigned short As[256 * 64];   // 32 KB
  __shared__ unsigned short Bs[128 * 64];   // 16 KB

  const int f    = blockIdx.x;           // 0..63
  const int pair = f & 7;
  const int nx   = f >> 3;               // 0..7
  const int b    = blockIdx.y;
  const int t    = threadIdx.x;

  const int l  = t & 63;
  const int w  = t >> 6;
  const int lr = l & 15;
  const int lk = l >> 4;
  const int lk16 = lk * 16;
  const int wm = w >> 1;                 // 0..3: 64-row group
  const int wn = w & 1;                  // 0..1: 64-col group

  const int n0 = nx * 128;
  const char* VTb = (const char*)(VT + (size_t)b * DIM * SEQ) + (size_t)n0 * 8192;

  for (int half = 0; half < 2; ++half){
    const int T  = half ? pair : (15 - pair);
    const int m0 = T * 256;
    const char* Ptb = (const char*)(Sp + (size_t)b * PBATCH + PANEL_OFF(T));
    const size_t Wb = (size_t)512 * (T + 1);   // panel row stride, bytes
    const int ksteps = 4 * (T + 1);

    f32x4 acc[4][4];
    #pragma unroll
    for (int i = 0; i < 4; ++i)
      #pragma unroll
      for (int j = 0; j < 4; ++j) acc[i][j] = (f32x4)0.0f;

    for (int s = 0; s < ksteps; ++s){
      // stage A: 256x64 from panel (2048 chunks, 4/thread)
      #pragma unroll
      for (int c = 0; c < 4; ++c){
        int id  = c * 512 + t;
        int row = id >> 3;
        int sw  = ((id & 7) * 16) ^ SWZB(row);
        g2l16((char*)As + (size_t)id * 16,
              Ptb + (size_t)row * Wb + s * 128 + sw);
      }
      // stage B: 128x64 from VT (1024 chunks, 2/thread)
      #pragma unroll
      for (int c = 0; c < 2; ++c){
        int id  = c * 512 + t;
        int row = id >> 3;
        int sw  = ((id & 7) * 16) ^ SWZB(row);
        g2l16((char*)Bs + (size_t)id * 16,
              VTb + (size_t)row * 8192 + s * 128 + sw);
      }
      WAITVM0;
      __syncthreads();
      #pragma unroll
      for (int ks = 0; ks < 2; ++ks){
        bf16x8 af[4], bfr[4];
        #pragma unroll
        for (int i = 0; i < 4; ++i){
          int ra = wm * 64 + i*16 + lr;
          int rb = wn * 64 + i*16 + lr;
          af[i]  = *(const bf16x8*)((const char*)As + (size_t)ra * 128
                                    + ((ks*64 + lk16) ^ SWZB(ra)));
          bfr[i] = *(const bf16x8*)((const char*)Bs + (size_t)rb * 128
                                    + ((ks*64 + lk16) ^ SWZB(rb)));
        }
        __builtin_amdgcn_s_setprio(1);
        #pragma unroll
        for (int i = 0; i < 4; ++i)
          #pragma unroll
          for (int j = 0; j < 4; ++j)
            acc[i][j] = mfma16(af[i], bfr[j], acc[i][j]);
        __builtin_amdgcn_s_setprio(0);
      }
      __syncthreads();
    }

    const float* lb = lrow + (size_t)b * SEQ + m0;
    float* ob = out + ((size_t)b * SEQ + m0) * DIM + n0;
    #pragma unroll
    for (int i = 0; i < 4; ++i)
      #pragma unroll
      for (int r = 0; r < 4; ++r){
        int row = wm * 64 + i*16 + lk*4 + r;
        float inv = 1.0f / lb[row];
        #pragma unroll
        for (int j = 0; j < 4; ++j)
          ob[(size_t)row * DIM + wn * 64 + j*16 + lr] = acc[i][j][r] * inv;
      }
  }
}

// ---------------- launch ----------------
extern "C" void kernel_launch(void* const* d_in, const int* in_sizes, int n_in,
                              void* d_out, int out_size, void* d_ws, size_t ws_size,
                              hipStream_t stream)
{
  (void)in_sizes; (void)n_in; (void)out_size; (void)ws_size;
  const float* emb = (const float*)d_in[0];
  const float* Wq  = (const float*)d_in[1];
  const float* Wk  = (const float*)d_in[2];
  const float* Wv  = (const float*)d_in[3];

  char* ws = (char*)d_ws;
  unsigned short* EB = (unsigned short*)ws;                    // 32MB (reused as VT)
  unsigned short* WB = (unsigned short*)(ws + 33554432);       // 6MB: Wq|Wk|Wv bf16
  unsigned short* Qb = (unsigned short*)(ws + 39845888);       // 32MB
  unsigned short* Kb = (unsigned short*)(ws + 73400320);       // 32MB
  unsigned short* Sp = (unsigned short*)(ws + 106954752);      // 71.3MB P panels
  float*          lr = (float*)(ws + 178257920);               // 64KB row sums
  unsigned short* Vb = (unsigned short*)d_out;                 // V scratch in out buffer
  unsigned short* VT = EB;                                     // alias: E dead after gemm

  hipMemsetAsync(lr, 0, (size_t)NB * SEQ * sizeof(float), stream);

  zero_holes<<<dim3(16, NB), 256, 0, stream>>>(Sp);
  cvt_all<<<19456, 256, 0, stream>>>(emb, Wq, Wk, Wv, EB, WB);

  gemm_qkv<<<768, 512, 0, stream>>>(EB, WB, Qb, Kb, Vb);
  transpose_v<<<dim3(64, 16, 4), 256, 0, stream>>>(Vb, VT);

  sp_gemm<<<dim3(528, NB), 256, 0, stream>>>(Qb, Kb, Sp, lr);
  pv_gemm<<<dim3(64, NB), 512, 0, stream>>>(Sp, VT, lr, (float*)d_out);
}

// Round 17
// 351.000 us; speedup vs baseline: 1.0019x; 1.0019x over previous
//
#include <hip/hip_runtime.h>
#include <math.h>
#include <stdint.h>

#define SEQ 4096
#define DIM 1024
#define NB  4
#define TRI  528              // 128-tile triangular count (sp indexing)

typedef __attribute__((ext_vector_type(8))) __bf16 bf16x8;
typedef __attribute__((ext_vector_type(4))) float  f32x4;
typedef __attribute__((ext_vector_type(4))) float  floatx4;
typedef __attribute__((ext_vector_type(8))) unsigned short ushortx8;
typedef __attribute__((ext_vector_type(4))) unsigned short ushortx4;

// panel layout for P: per batch, 16 panels; panel T = 256 rows x 256(T+1) cols
// elem offset of panel T: 32768*T*(T+1); batch stride = 8912896 elems
#define PANEL_OFF(T)  ((size_t)32768 * (T) * ((T) + 1))
#define PBATCH        ((size_t)8912896)

__device__ __forceinline__ unsigned short f2bf(float f){
  union { float f; unsigned int u; } c; c.f = f;
  unsigned int u = c.u;
  return (unsigned short)((u + 0x7fffu + ((u >> 16) & 1u)) >> 16);
}

__device__ __forceinline__ f32x4 mfma16(bf16x8 a, bf16x8 b, f32x4 c){
  return __builtin_amdgcn_mfma_f32_16x16x32_bf16(a, b, c, 0, 0, 0);
}

__device__ __forceinline__ void g2l16(void* lds, const void* g){
  __builtin_amdgcn_global_load_lds(
      (const __attribute__((address_space(1))) unsigned int*)g,
      (__attribute__((address_space(3))) unsigned int*)lds, 16, 0, 0);
}

#define WAITVM0 asm volatile("s_waitcnt vmcnt(0)" ::: "memory")

#define BARRAW() do { asm volatile("" ::: "memory"); \
  __builtin_amdgcn_s_barrier(); asm volatile("" ::: "memory"); } while (0)
#define VM6_BAR() do { asm volatile("s_waitcnt vmcnt(6)" ::: "memory"); \
  __builtin_amdgcn_s_barrier(); asm volatile("" ::: "memory"); } while (0)
#define LGKM0() do { asm volatile("s_waitcnt lgkmcnt(0)" ::: "memory"); \
  __builtin_amdgcn_sched_barrier(0); } while (0)

#define SWZB(r) (((r) & 7) << 4)

// stage one 128x64 bf16 tile (sp kernel; linear LDS dest, swizzled source)
#define STAGE_AB(Aptr, Astr, Bptr, Bstr) do { \
  _Pragma("unroll") \
  for (int _c = 0; _c < 4; ++_c){ \
    int _id  = _c * 256 + t; \
    int _row = _id >> 3; \
    int _sw  = ((_id & 7) * 16) ^ SWZB(_row); \
    g2l16((char*)As + (size_t)_id * 16, \
          (const char*)(Aptr) + (size_t)_row * (Astr) + _sw); \
    g2l16((char*)Bs + (size_t)_id * 16, \
          (const char*)(Bptr) + (size_t)_row * (Bstr) + _sw); \
  } \
} while (0)

// 128x128-tile MFMA step (sp kernel)
#define COMPUTE128S() do { \
  _Pragma("unroll") \
  for (int _ks = 0; _ks < 2; ++_ks){ \
    bf16x8 _af[4], _bf[4]; \
    _Pragma("unroll") \
    for (int _i = 0; _i < 4; ++_i){ \
      int _ra = wr + _i*16 + lr; \
      int _rb = wc + _i*16 + lr; \
      _af[_i] = *(const bf16x8*)((const char*)As + (size_t)_ra * 128 \
                                 + ((_ks*64 + lk16) ^ SWZB(_ra))); \
      _bf[_i] = *(const bf16x8*)((const char*)Bs + (size_t)_rb * 128 \
                                 + ((_ks*64 + lk16) ^ SWZB(_rb))); \
    } \
    __builtin_amdgcn_s_setprio(1); \
    _Pragma("unroll") \
    for (int _i = 0; _i < 4; ++_i) \
      _Pragma("unroll") \
      for (int _j = 0; _j < 4; ++_j) \
        acc[_i][_j] = mfma16(_af[_i], _bf[_j], acc[_i][_j]); \
    __builtin_amdgcn_s_setprio(0); \
  } \
} while (0)

// ================= 8-phase 256x256 GEMM core (qkv only; r14/r15-measured) ==
#define HT_STAGE(DST, SRC, KT, KH) do {                                   \
  g2l16((DST) + (size_t)t * 16,         (SRC) + so0 + (KT)*128 + (KH)*64);\
  g2l16((DST) + (size_t)(512 + t) * 16, (SRC) + so1 + (KT)*128 + (KH)*64);\
} while (0)

#define MFMA16X(NH) do {                                                  \
  __builtin_amdgcn_s_setprio(1);                                          \
  _Pragma("unroll")                                                       \
  for (int i = 0; i < 8; ++i){                                            \
    acc[i][(NH)*2]     = mfma16(af[i], b0, acc[i][(NH)*2]);               \
    acc[i][(NH)*2 + 1] = mfma16(af[i], b1, acc[i][(NH)*2 + 1]);           \
  }                                                                       \
  __builtin_amdgcn_s_setprio(0);                                          \
} while (0)

#define CORE8PH(ASRC, BSRC)                                               \
  f32x4 acc[8][4];                                                        \
  _Pragma("unroll")                                                       \
  for (int i = 0; i < 8; ++i)                                             \
    _Pragma("unroll")                                                     \
    for (int j = 0; j < 4; ++j) acc[i][j] = (f32x4)0.0f;                  \
  int aoff[8], boff[4];                                                   \
  _Pragma("unroll")                                                       \
  for (int i = 0; i < 8; ++i){                                            \
    int rr = wm*128 + i*16 + lr;                                          \
    aoff[i] = (rr>>1)*128 + ((((rr&1)*4 + lk) ^ ((rr>>1)&7))*16);         \
  }                                                                       \
  _Pragma("unroll")                                                       \
  for (int j = 0; j < 4; ++j){                                            \
    int rr = wn*64 + j*16 + lr;                                           \
    boff[j] = 32768 + (rr>>1)*128 + ((((rr&1)*4 + lk) ^ ((rr>>1)&7))*16); \
  }                                                                       \
  int so0, so1;                                                           \
  {                                                                       \
    int L0 = t >> 3,        sx0 = (t & 7) ^ (L0 & 7);                     \
    so0 = (2*L0 + (sx0>>2))*2048 + (sx0&3)*16;                            \
    int L1 = (512+t) >> 3,  sx1 = ((512+t) & 7) ^ (L1 & 7);               \
    so1 = (2*L1 + (sx1>>2))*2048 + (sx1&3)*16;                            \
  }                                                                       \
  HT_STAGE(ldsb,          ASRC, 0, 0);                                    \
  HT_STAGE(ldsb + 32768,  BSRC, 0, 0);                                    \
  HT_STAGE(ldsb + 16384,  ASRC, 0, 1);                                    \
  HT_STAGE(ldsb + 49152,  BSRC, 0, 1);                                    \
  HT_STAGE(ldsb + 65536,  ASRC, 1, 0);                                    \
  HT_STAGE(ldsb + 98304,  BSRC, 1, 0);                                    \
  asm volatile("s_waitcnt vmcnt(8)" ::: "memory");                        \
  __builtin_amdgcn_s_barrier();                                           \
  asm volatile("" ::: "memory");                                          \
  for (int U = 0; U < 15; ++U){                                           \
    char* bufc = ldsb + (size_t)(U & 1) * 65536;                          \
    char* bufn = ldsb + (size_t)((U + 1) & 1) * 65536;                    \
    bf16x8 af[8], b0, b1;                                                 \
    _Pragma("unroll")                                                     \
    for (int i = 0; i < 8; ++i) af[i] = *(const bf16x8*)(bufc + aoff[i]); \
    b0 = *(const bf16x8*)(bufc + boff[0]);                                \
    b1 = *(const bf16x8*)(bufc + boff[1]);                                \
    HT_STAGE(bufn + 16384, ASRC, U + 1, 1);                               \
    BARRAW(); LGKM0();                                                    \
    MFMA16X(0);                                                           \
    BARRAW();                                                             \
    b0 = *(const bf16x8*)(bufc + boff[2]);                                \
    b1 = *(const bf16x8*)(bufc + boff[3]);                                \
    HT_STAGE(bufn + 49152, BSRC, U + 1, 1);                               \
    BARRAW(); LGKM0();                                                    \
    MFMA16X(1);                                                           \
    VM6_BAR();                                                            \
    _Pragma("unroll")                                                     \
    for (int i = 0; i < 8; ++i)                                           \
      af[i] = *(const bf16x8*)(bufc + 16384 + aoff[i]);                   \
    b0 = *(const bf16x8*)(bufc + boff[0] + 16384);                        \
    b1 = *(const bf16x8*)(bufc + boff[1] + 16384);                        \
    if (U < 14) HT_STAGE(bufc, ASRC, U + 2, 0);                           \
    BARRAW(); LGKM0();                                                    \
    MFMA16X(0);                                                           \
    BARRAW();                                                             \
    b0 = *(const bf16x8*)(bufc + boff[2] + 16384);                        \
    b1 = *(const bf16x8*)(bufc + boff[3] + 16384);                        \
    if (U < 14) HT_STAGE(bufc + 32768, BSRC, U + 2, 0);                   \
    BARRAW(); LGKM0();                                                    \
    MFMA16X(1);                                                           \
    VM6_BAR();                                                            \
  }                                                                       \
  {                                                                       \
    char* bufc = ldsb + 65536;                                            \
    WAITVM0;                                                              \
    __builtin_amdgcn_s_barrier();                                         \
    asm volatile("" ::: "memory");                                        \
    _Pragma("unroll")                                                     \
    for (int ks = 0; ks < 2; ++ks){                                       \
      bf16x8 af[8], b0, b1;                                               \
      _Pragma("unroll")                                                   \
      for (int i = 0; i < 8; ++i)                                         \
        af[i] = *(const bf16x8*)(bufc + ks*16384 + aoff[i]);              \
      _Pragma("unroll")                                                   \
      for (int j = 0; j < 4; j += 2){                                     \
        b0 = *(const bf16x8*)(bufc + boff[j]   + ks*16384);               \
        b1 = *(const bf16x8*)(bufc + boff[j+1] + ks*16384);               \
        _Pragma("unroll")                                                 \
        for (int i = 0; i < 8; ++i){                                      \
          acc[i][j]   = mfma16(af[i], b0, acc[i][j]);                     \
          acc[i][j+1] = mfma16(af[i], b1, acc[i][j+1]);                   \
        }                                                                 \
      }                                                                   \
    }                                                                     \
  }

// ---------------- fp32 -> bf16 conversion (all 4 inputs fused) ------------
__global__ void cvt_all(const float* __restrict__ emb,
                        const float* __restrict__ Wq,
                        const float* __restrict__ Wk,
                        const float* __restrict__ Wv,
                        unsigned short* __restrict__ EB,
                        unsigned short* __restrict__ WB){
  int i = blockIdx.x * blockDim.x + threadIdx.x;
  const float* src;
  unsigned short* dst;
  int idx;
  if (i < 4194304){ src = emb; dst = EB; idx = i; }
  else {
    int j = i - 4194304;
    int w = j >> 18;           // 0..2
    idx = j & 262143;
    src = w == 0 ? Wq : (w == 1 ? Wk : Wv);
    dst = WB + (size_t)w * 1048576;
  }
  floatx4 v = *((const floatx4*)src + idx);
  ushortx4 o;
  o[0] = f2bf(v[0]); o[1] = f2bf(v[1]); o[2] = f2bf(v[2]); o[3] = f2bf(v[3]);
  *((ushortx4*)dst + idx) = o;
}

// ---------------- zero panel holes: panel T rows 0..127, last 128 cols ----
__global__ __launch_bounds__(256) void zero_holes(unsigned short* __restrict__ Sp){
  const int T = blockIdx.x;
  const int b = blockIdx.y;
  unsigned short* Pp = Sp + b * PBATCH + PANEL_OFF(T);
  const int W = 256 * (T + 1);
  const int c0 = (2 * T + 1) * 128;
  const int t = threadIdx.x;
  #pragma unroll
  for (int k = 0; k < 8; ++k){
    int v = k * 256 + t;          // 0..2047
    int row = v >> 4;
    int col = (v & 15) * 8;
    *(ushortx8*)&Pp[(size_t)row * W + c0 + col] = (ushortx8)0;
  }
}

// ---------------- QKV projection GEMM: 256^2 8-phase + XCD remap (r15) ----
__global__ __launch_bounds__(512, 1) void gemm_qkv(
    const unsigned short* __restrict__ E,
    const unsigned short* __restrict__ W3,
    unsigned short* __restrict__ Qd,
    unsigned short* __restrict__ Kd,
    unsigned short* __restrict__ Vd)
{
  __shared__ char ldsbuf[131072];
  char* ldsb = ldsbuf;

  const int bid = blockIdx.x;          // 0..767
  const int xcd = bid & 7;
  const int s   = bid >> 3;            // 0..95
  const int ml  = s / 12;
  const int r12 = s - ml * 12;
  const int mt  = xcd * 8 + ml;        // 0..63
  const int nt  = r12 & 3;             // 0..3
  const int z   = r12 >> 2;            // 0..2

  const int m0 = mt * 256;
  const int n0 = nt * 256;
  const unsigned short* W = W3 + (size_t)z * (DIM * (size_t)DIM);
  unsigned short* dst = z == 0 ? Qd : (z == 1 ? Kd : Vd);

  const int t  = threadIdx.x;
  const int w  = t >> 6;
  const int l  = t & 63;
  const int lr = l & 15;
  const int lk = l >> 4;
  const int wm = w >> 2;
  const int wn = w & 3;

  const char* Asl = (const char*)E + (size_t)m0 * 2048;
  const char* Bsl = (const char*)W + (size_t)n0 * 2048;

  CORE8PH(Asl, Bsl);

  #pragma unroll
  for (int i = 0; i < 8; ++i)
    #pragma unroll
    for (int j = 0; j < 4; ++j)
      #pragma unroll
      for (int r = 0; r < 4; ++r){
        int row = wm * 128 + i * 16 + lk * 4 + r;
        int col = wn * 64 + j * 16 + lr;
        dst[(size_t)(m0 + row) * DIM + n0 + col] = f2bf(acc[i][j][r]);
      }
}

// ---------------- V transpose ----------------
__global__ __launch_bounds__(256) void transpose_v(
    const unsigned short* __restrict__ V, unsigned short* __restrict__ VT)
{
  __shared__ unsigned short T[64][72];
  const int b  = blockIdx.z;
  const int s0 = blockIdx.x * 64;
  const int a0 = blockIdx.y * 64;
  const unsigned short* Vb = V + (size_t)b * SEQ * DIM;
  unsigned short* VTb = VT + (size_t)b * DIM * SEQ;
  const int t = threadIdx.x;
  const int r = t >> 3, cg = t & 7;
  #pragma unroll
  for (int p = 0; p < 2; ++p){
    int row = r + p * 32;
    ushortx8 v = *(const ushortx8*)(Vb + (size_t)(s0 + row) * DIM + a0 + cg*8);
    *(ushortx8*)&T[row][cg*8] = v;
  }
  __syncthreads();
  #pragma unroll
  for (int p = 0; p < 2; ++p){
    int ar = r + p * 32;
    ushortx8 o;
    #pragma unroll
    for (int j = 0; j < 8; ++j) o[j] = T[cg*8 + j][ar];
    *(ushortx8*)(VTb + (size_t)(a0 + ar) * SEQ + s0 + cg*8) = o;
  }
}

// ---------------- S/P GEMM: r15 form; writes P into panel layout ----------
__global__ __launch_bounds__(256, 2) void sp_gemm(
    const unsigned short* __restrict__ Q,
    const unsigned short* __restrict__ K,
    unsigned short* __restrict__ Sp,
    float* __restrict__ lrow)
{
  const int orig = blockIdx.x;         // 0..527
  const int p    = (orig & 7) * 66 + (orig >> 3);
  const int b    = blockIdx.y;

  int ti = (int)((__builtin_sqrtf(8.0f * (float)p + 1.0f) - 1.0f) * 0.5f);
  while ((ti + 1) * (ti + 2) / 2 <= p) ++ti;
  while (ti * (ti + 1) / 2 > p) --ti;
  const int tj = p - ti * (ti + 1) / 2;

  __shared__ unsigned short As[128 * 64];
  __shared__ unsigned short Bs[128 * 64];

  const int t  = threadIdx.x;
  const int m0 = ti * 128;
  const int n0 = tj * 128;

  const int l  = t & 63;
  const int w  = t >> 6;
  const int lr = l & 15;
  const int lk = l >> 4;
  const int lk16 = lk * 16;
  const int wr = (w >> 1) * 64;
  const int wc = (w & 1) * 64;

  const char* Abase = (const char*)(Q + (size_t)b * SEQ * DIM) + (size_t)m0 * 2048;
  const char* Bbase = (const char*)(K + (size_t)b * SEQ * DIM) + (size_t)n0 * 2048;

  f32x4 acc[4][4];
  #pragma unroll
  for (int i = 0; i < 4; ++i)
    #pragma unroll
    for (int j = 0; j < 4; ++j) acc[i][j] = (f32x4)0.0f;

  for (int kt = 0; kt < DIM / 64; ++kt){
    STAGE_AB(Abase + kt * 128, 2048, Bbase + kt * 128, 2048);
    WAITVM0;
    __syncthreads();
    COMPUTE128S();
    __syncthreads();
  }

  // epilogue: P = exp(scale*acc) masked; write into panel layout; row sums
  const float scale = 0.03125f;  // 1/sqrt(1024)
  const int Tp = ti >> 1;
  const int Wp = 256 * (Tp + 1);
  const int rowbase = (ti & 1) * 128;
  unsigned short* Pp = Sp + (size_t)b * PBATCH + PANEL_OFF(Tp);
  float* lb = lrow + (size_t)b * SEQ + m0;

  #pragma unroll
  for (int i = 0; i < 4; ++i){
    float rs[4] = {0.f, 0.f, 0.f, 0.f};
    #pragma unroll
    for (int j = 0; j < 4; ++j){
      #pragma unroll
      for (int r = 0; r < 4; ++r){
        int row = wr + i*16 + lk*4 + r;
        int col = wc + j*16 + lr;
        float pv = 0.0f;
        if (n0 + col <= m0 + row) pv = __expf(acc[i][j][r] * scale);
        rs[r] += pv;
        Pp[(size_t)(rowbase + row) * Wp + n0 + col] = f2bf(pv);
      }
    }
    #pragma unroll
    for (int r = 0; r < 4; ++r){
      float v = rs[r];
      v += __shfl_xor(v, 1, 64);
      v += __shfl_xor(v, 2, 64);
      v += __shfl_xor(v, 4, 64);
      v += __shfl_xor(v, 8, 64);
      if (lr == 0)
        atomicAdd(&lb[wr + i*16 + lk*4 + r], v);
    }
  }
}

// ---------------- PV GEMM v2: M=256 panel tiles, N=128; O = (P V)/l --------
// grid (64, NB), 512 thr (8 waves: wm=w>>1 row-quarter, wn=w&1 col-half).
// f chunked: xcd = f&7 -> pair = xcd (P-panels L2-shared), nx = f>>3.
// Per block: panels (15-pair) then (pair); ksteps 4(T+1) each (68 total).
__global__ __launch_bounds__(512, 1) void pv_gemm(
    const unsigned short* __restrict__ Sp,
    const unsigned short* __restrict__ VT,
    const float* __restrict__ lrow,
    float* __restrict__ out)
{
  __shared__ unsigned short As[256 * 64];   // 32 KB
  __shared__ unsigned short Bs[128 * 64];   // 16 KB

  const int f    = blockIdx.x;           // 0..63
  const int pair = f & 7;
  const int nx   = f >> 3;               // 0..7
  const int b    = blockIdx.y;
  const int t    = threadIdx.x;

  const int l  = t & 63;
  const int w  = t >> 6;
  const int lr = l & 15;
  const int lk = l >> 4;
  const int lk16 = lk * 16;
  const int wm = w >> 1;                 // 0..3: 64-row group
  const int wn = w & 1;                  // 0..1: 64-col group

  const int n0 = nx * 128;
  const char* VTb = (const char*)(VT + (size_t)b * DIM * SEQ) + (size_t)n0 * 8192;

  for (int half = 0; half < 2; ++half){
    const int T  = half ? pair : (15 - pair);
    const int m0 = T * 256;
    const char* Ptb = (const char*)(Sp + (size_t)b * PBATCH + PANEL_OFF(T));
    const size_t Wb = (size_t)512 * (T + 1);   // panel row stride, bytes
    const int ksteps = 4 * (T + 1);

    f32x4 acc[4][4];
    #pragma unroll
    for (int i = 0; i < 4; ++i)
      #pragma unroll
      for (int j = 0; j < 4; ++j) acc[i][j] = (f32x4)0.0f;

    for (int s = 0; s < ksteps; ++s){
      // stage A: 256x64 from panel (2048 chunks, 4/thread)
      #pragma unroll
      for (int c = 0; c < 4; ++c){
        int id  = c * 512 + t;
        int row = id >> 3;
        int sw  = ((id & 7) * 16) ^ SWZB(row);
        g2l16((char*)As + (size_t)id * 16,
              Ptb + (size_t)row * Wb + s * 128 + sw);
      }
      // stage B: 128x64 from VT (1024 chunks, 2/thread)
      #pragma unroll
      for (int c = 0; c < 2; ++c){
        int id  = c * 512 + t;
        int row = id >> 3;
        int sw  = ((id & 7) * 16) ^ SWZB(row);
        g2l16((char*)Bs + (size_t)id * 16,
              VTb + (size_t)row * 8192 + s * 128 + sw);
      }
      WAITVM0;
      __syncthreads();
      #pragma unroll
      for (int ks = 0; ks < 2; ++ks){
        bf16x8 af[4], bfr[4];
        #pragma unroll
        for (int i = 0; i < 4; ++i){
          int ra = wm * 64 + i*16 + lr;
          int rb = wn * 64 + i*16 + lr;
          af[i]  = *(const bf16x8*)((const char*)As + (size_t)ra * 128
                                    + ((ks*64 + lk16) ^ SWZB(ra)));
          bfr[i] = *(const bf16x8*)((const char*)Bs + (size_t)rb * 128
                                    + ((ks*64 + lk16) ^ SWZB(rb)));
        }
        __builtin_amdgcn_s_setprio(1);
        #pragma unroll
        for (int i = 0; i < 4; ++i)
          #pragma unroll
          for (int j = 0; j < 4; ++j)
            acc[i][j] = mfma16(af[i], bfr[j], acc[i][j]);
        __builtin_amdgcn_s_setprio(0);
      }
      __syncthreads();
    }

    const float* lb = lrow + (size_t)b * SEQ + m0;
    float* ob = out + ((size_t)b * SEQ + m0) * DIM + n0;
    #pragma unroll
    for (int i = 0; i < 4; ++i)
      #pragma unroll
      for (int r = 0; r < 4; ++r){
        int row = wm * 64 + i*16 + lk*4 + r;
        float inv = 1.0f / lb[row];
        #pragma unroll
        for (int j = 0; j < 4; ++j)
          ob[(size_t)row * DIM + wn * 64 + j*16 + lr] = acc[i][j][r] * inv;
      }
  }
}

// ---------------- launch ----------------
extern "C" void kernel_launch(void* const* d_in, const int* in_sizes, int n_in,
                              void* d_out, int out_size, void* d_ws, size_t ws_size,
                              hipStream_t stream)
{
  (void)in_sizes; (void)n_in; (void)out_size; (void)ws_size;
  const float* emb = (const float*)d_in[0];
  const float* Wq  = (const float*)d_in[1];
  const float* Wk  = (const float*)d_in[2];
  const float* Wv  = (const float*)d_in[3];

  char* ws = (char*)d_ws;
  unsigned short* EB = (unsigned short*)ws;                    // 32MB (reused as VT)
  unsigned short* WB = (unsigned short*)(ws + 33554432);       // 6MB: Wq|Wk|Wv bf16
  unsigned short* Qb = (unsigned short*)(ws + 39845888);       // 32MB
  unsigned short* Kb = (unsigned short*)(ws + 73400320);       // 32MB
  unsigned short* Sp = (unsigned short*)(ws + 106954752);      // 71.3MB P panels
  float*          lr = (float*)(ws + 178257920);               // 64KB row sums
  unsigned short* Vb = (unsigned short*)d_out;                 // V scratch in out buffer
  unsigned short* VT = EB;                                     // alias: E dead after gemm

  hipMemsetAsync(lr, 0, (size_t)NB * SEQ * sizeof(float), stream);

  zero_holes<<<dim3(16, NB), 256, 0, stream>>>(Sp);
  cvt_all<<<19456, 256, 0, stream>>>(emb, Wq, Wk, Wv, EB, WB);

  gemm_qkv<<<768, 512, 0, stream>>>(EB, WB, Qb, Kb, Vb);
  transpose_v<<<dim3(64, 16, 4), 256, 0, stream>>>(Vb, VT);

  sp_gemm<<<dim3(528, NB), 256, 0, stream>>>(Qb, Kb, Sp, lr);
  pv_gemm<<<dim3(64, NB), 512, 0, stream>>>(Sp, VT, lr, (float*)d_out);
}

// Round 18
// 321.278 us; speedup vs baseline: 1.0946x; 1.0925x over previous
//
#include <hip/hip_runtime.h>
#include <math.h>
#include <stdint.h>

#define SEQ 4096
#define DIM 1024
#define NB  4
#define TRI  528              // NTILE*(NTILE+1)/2 packed causal tiles

typedef __attribute__((ext_vector_type(8))) __bf16 bf16x8;
typedef __attribute__((ext_vector_type(4))) float  f32x4;
typedef __attribute__((ext_vector_type(4))) float  floatx4;
typedef __attribute__((ext_vector_type(8))) unsigned short ushortx8;
typedef __attribute__((ext_vector_type(4))) unsigned short ushortx4;

__device__ __forceinline__ unsigned short f2bf(float f){
  union { float f; unsigned int u; } c; c.f = f;
  unsigned int u = c.u;
  return (unsigned short)((u + 0x7fffu + ((u >> 16) & 1u)) >> 16);
}

__device__ __forceinline__ f32x4 mfma16(bf16x8 a, bf16x8 b, f32x4 c){
  return __builtin_amdgcn_mfma_f32_16x16x32_bf16(a, b, c, 0, 0, 0);
}

__device__ __forceinline__ void g2l16(void* lds, const void* g){
  __builtin_amdgcn_global_load_lds(
      (const __attribute__((address_space(1))) unsigned int*)g,
      (__attribute__((address_space(3))) unsigned int*)lds, 16, 0, 0);
}

#define WAITVM0 asm volatile("s_waitcnt vmcnt(0)" ::: "memory")

#define BARRAW() do { asm volatile("" ::: "memory"); \
  __builtin_amdgcn_s_barrier(); asm volatile("" ::: "memory"); } while (0)
#define VM6_BAR() do { asm volatile("s_waitcnt vmcnt(6)" ::: "memory"); \
  __builtin_amdgcn_s_barrier(); asm volatile("" ::: "memory"); } while (0)
#define LGKM0() do { asm volatile("s_waitcnt lgkmcnt(0)" ::: "memory"); \
  __builtin_amdgcn_sched_barrier(0); } while (0)

#define SWZB(r) (((r) & 7) << 4)

// stage one 128x64 bf16 tile (linear LDS dest, pre-swizzled global source)
#define STAGE_AB(Aptr, Astr, Bptr, Bstr) do { \
  _Pragma("unroll") \
  for (int _c = 0; _c < 4; ++_c){ \
    int _id  = _c * 256 + t; \
    int _row = _id >> 3; \
    int _sw  = ((_id & 7) * 16) ^ SWZB(_row); \
    g2l16((char*)As + (size_t)_id * 16, \
          (const char*)(Aptr) + (size_t)_row * (Astr) + _sw); \
    g2l16((char*)Bs + (size_t)_id * 16, \
          (const char*)(Bptr) + (size_t)_row * (Bstr) + _sw); \
  } \
} while (0)

// 128x128-tile MFMA step over one staged 64-K slab (swizzled ds_reads)
#define COMPUTE128S() do { \
  _Pragma("unroll") \
  for (int _ks = 0; _ks < 2; ++_ks){ \
    bf16x8 _af[4], _bf[4]; \
    _Pragma("unroll") \
    for (int _i = 0; _i < 4; ++_i){ \
      int _ra = wr + _i*16 + lr; \
      int _rb = wc + _i*16 + lr; \
      _af[_i] = *(const bf16x8*)((const char*)As + (size_t)_ra * 128 \
                                 + ((_ks*64 + lk16) ^ SWZB(_ra))); \
      _bf[_i] = *(const bf16x8*)((const char*)Bs + (size_t)_rb * 128 \
                                 + ((_ks*64 + lk16) ^ SWZB(_rb))); \
    } \
    __builtin_amdgcn_s_setprio(1); \
    _Pragma("unroll") \
    for (int _i = 0; _i < 4; ++_i) \
      _Pragma("unroll") \
      for (int _j = 0; _j < 4; ++_j) \
        acc[_i][_j] = mfma16(_af[_i], _bf[_j], acc[_i][_j]); \
    __builtin_amdgcn_s_setprio(0); \
  } \
} while (0)

// ================= 8-phase 256x256 GEMM core (qkv only; r14/r15-measured) ==
#define HT_STAGE(DST, SRC, KT, KH) do {                                   \
  g2l16((DST) + (size_t)t * 16,         (SRC) + so0 + (KT)*128 + (KH)*64);\
  g2l16((DST) + (size_t)(512 + t) * 16, (SRC) + so1 + (KT)*128 + (KH)*64);\
} while (0)

#define MFMA16X(NH) do {                                                  \
  __builtin_amdgcn_s_setprio(1);                                          \
  _Pragma("unroll")                                                       \
  for (int i = 0; i < 8; ++i){                                            \
    acc[i][(NH)*2]     = mfma16(af[i], b0, acc[i][(NH)*2]);               \
    acc[i][(NH)*2 + 1] = mfma16(af[i], b1, acc[i][(NH)*2 + 1]);           \
  }                                                                       \
  __builtin_amdgcn_s_setprio(0);                                          \
} while (0)

#define CORE8PH(ASRC, BSRC)                                               \
  f32x4 acc[8][4];                                                        \
  _Pragma("unroll")                                                       \
  for (int i = 0; i < 8; ++i)                                             \
    _Pragma("unroll")                                                     \
    for (int j = 0; j < 4; ++j) acc[i][j] = (f32x4)0.0f;                  \
  int aoff[8], boff[4];                                                   \
  _Pragma("unroll")                                                       \
  for (int i = 0; i < 8; ++i){                                            \
    int rr = wm*128 + i*16 + lr;                                          \
    aoff[i] = (rr>>1)*128 + ((((rr&1)*4 + lk) ^ ((rr>>1)&7))*16);         \
  }                                                                       \
  _Pragma("unroll")                                                       \
  for (int j = 0; j < 4; ++j){                                            \
    int rr = wn*64 + j*16 + lr;                                           \
    boff[j] = 32768 + (rr>>1)*128 + ((((rr&1)*4 + lk) ^ ((rr>>1)&7))*16); \
  }                                                                       \
  int so0, so1;                                                           \
  {                                                                       \
    int L0 = t >> 3,        sx0 = (t & 7) ^ (L0 & 7);                     \
    so0 = (2*L0 + (sx0>>2))*2048 + (sx0&3)*16;                            \
    int L1 = (512+t) >> 3,  sx1 = ((512+t) & 7) ^ (L1 & 7);               \
    so1 = (2*L1 + (sx1>>2))*2048 + (sx1&3)*16;                            \
  }                                                                       \
  HT_STAGE(ldsb,          ASRC, 0, 0);                                    \
  HT_STAGE(ldsb + 32768,  BSRC, 0, 0);                                    \
  HT_STAGE(ldsb + 16384,  ASRC, 0, 1);                                    \
  HT_STAGE(ldsb + 49152,  BSRC, 0, 1);                                    \
  HT_STAGE(ldsb + 65536,  ASRC, 1, 0);                                    \
  HT_STAGE(ldsb + 98304,  BSRC, 1, 0);                                    \
  asm volatile("s_waitcnt vmcnt(8)" ::: "memory");                        \
  __builtin_amdgcn_s_barrier();                                           \
  asm volatile("" ::: "memory");                                          \
  for (int U = 0; U < 15; ++U){                                           \
    char* bufc = ldsb + (size_t)(U & 1) * 65536;                          \
    char* bufn = ldsb + (size_t)((U + 1) & 1) * 65536;                    \
    bf16x8 af[8], b0, b1;                                                 \
    _Pragma("unroll")                                                     \
    for (int i = 0; i < 8; ++i) af[i] = *(const bf16x8*)(bufc + aoff[i]); \
    b0 = *(const bf16x8*)(bufc + boff[0]);                                \
    b1 = *(const bf16x8*)(bufc + boff[1]);                                \
    HT_STAGE(bufn + 16384, ASRC, U + 1, 1);                               \
    BARRAW(); LGKM0();                                                    \
    MFMA16X(0);                                                           \
    BARRAW();                                                             \
    b0 = *(const bf16x8*)(bufc + boff[2]);                                \
    b1 = *(const bf16x8*)(bufc + boff[3]);                                \
    HT_STAGE(bufn + 49152, BSRC, U + 1, 1);                               \
    BARRAW(); LGKM0();                                                    \
    MFMA16X(1);                                                           \
    VM6_BAR();                                                            \
    _Pragma("unroll")                                                     \
    for (int i = 0; i < 8; ++i)                                           \
      af[i] = *(const bf16x8*)(bufc + 16384 + aoff[i]);                   \
    b0 = *(const bf16x8*)(bufc + boff[0] + 16384);                        \
    b1 = *(const bf16x8*)(bufc + boff[1] + 16384);                        \
    if (U < 14) HT_STAGE(bufc, ASRC, U + 2, 0);                           \
    BARRAW(); LGKM0();                                                    \
    MFMA16X(0);                                                           \
    BARRAW();                                                             \
    b0 = *(const bf16x8*)(bufc + boff[2] + 16384);                        \
    b1 = *(const bf16x8*)(bufc + boff[3] + 16384);                        \
    if (U < 14) HT_STAGE(bufc + 32768, BSRC, U + 2, 0);                   \
    BARRAW(); LGKM0();                                                    \
    MFMA16X(1);                                                           \
    VM6_BAR();                                                            \
  }                                                                       \
  {                                                                       \
    char* bufc = ldsb + 65536;                                            \
    WAITVM0;                                                              \
    __builtin_amdgcn_s_barrier();                                         \
    asm volatile("" ::: "memory");                                        \
    _Pragma("unroll")                                                     \
    for (int ks = 0; ks < 2; ++ks){                                       \
      bf16x8 af[8], b0, b1;                                               \
      _Pragma("unroll")                                                   \
      for (int i = 0; i < 8; ++i)                                         \
        af[i] = *(const bf16x8*)(bufc + ks*16384 + aoff[i]);              \
      _Pragma("unroll")                                                   \
      for (int j = 0; j < 4; j += 2){                                     \
        b0 = *(const bf16x8*)(bufc + boff[j]   + ks*16384);               \
        b1 = *(const bf16x8*)(bufc + boff[j+1] + ks*16384);               \
        _Pragma("unroll")                                                 \
        for (int i = 0; i < 8; ++i){                                      \
          acc[i][j]   = mfma16(af[i], b0, acc[i][j]);                     \
          acc[i][j+1] = mfma16(af[i], b1, acc[i][j+1]);                   \
        }                                                                 \
      }                                                                   \
    }                                                                     \
  }

// ---------------- fp32 -> bf16 conversion (all 4 inputs, 1 launch) --------
__global__ void cvt_all(const float* __restrict__ emb,
                        const float* __restrict__ Wq,
                        const float* __restrict__ Wk,
                        const float* __restrict__ Wv,
                        unsigned short* __restrict__ EB,
                        unsigned short* __restrict__ WB){
  int i = blockIdx.x * blockDim.x + threadIdx.x;
  const float* src;
  unsigned short* dst;
  int idx;
  if (i < 4194304){ src = emb; dst = EB; idx = i; }
  else {
    int j = i - 4194304;
    int w = j >> 18;           // 0..2
    idx = j & 262143;
    src = w == 0 ? Wq : (w == 1 ? Wk : Wv);
    dst = WB + (size_t)w * 1048576;
  }
  floatx4 v = *((const floatx4*)src + idx);
  ushortx4 o;
  o[0] = f2bf(v[0]); o[1] = f2bf(v[1]); o[2] = f2bf(v[2]); o[3] = f2bf(v[3]);
  *((ushortx4*)dst + idx) = o;
}

// ---------------- QKV projection GEMM: 256^2 8-phase + XCD remap ----------
__global__ __launch_bounds__(512, 1) void gemm_qkv(
    const unsigned short* __restrict__ E,
    const unsigned short* __restrict__ W3,
    unsigned short* __restrict__ Qd,
    unsigned short* __restrict__ Kd,
    unsigned short* __restrict__ Vd)
{
  __shared__ char ldsbuf[131072];
  char* ldsb = ldsbuf;

  const int bid = blockIdx.x;          // 0..767
  const int xcd = bid & 7;
  const int s   = bid >> 3;            // 0..95
  const int ml  = s / 12;
  const int r12 = s - ml * 12;
  const int mt  = xcd * 8 + ml;        // 0..63
  const int nt  = r12 & 3;             // 0..3
  const int z   = r12 >> 2;            // 0..2

  const int m0 = mt * 256;
  const int n0 = nt * 256;
  const unsigned short* W = W3 + (size_t)z * (DIM * (size_t)DIM);
  unsigned short* dst = z == 0 ? Qd : (z == 1 ? Kd : Vd);

  const int t  = threadIdx.x;
  const int w  = t >> 6;
  const int l  = t & 63;
  const int lr = l & 15;
  const int lk = l >> 4;
  const int wm = w >> 2;
  const int wn = w & 3;

  const char* Asl = (const char*)E + (size_t)m0 * 2048;
  const char* Bsl = (const char*)W + (size_t)n0 * 2048;

  CORE8PH(Asl, Bsl);

  #pragma unroll
  for (int i = 0; i < 8; ++i)
    #pragma unroll
    for (int j = 0; j < 4; ++j)
      #pragma unroll
      for (int r = 0; r < 4; ++r){
        int row = wm * 128 + i * 16 + lk * 4 + r;
        int col = wn * 64 + j * 16 + lr;
        dst[(size_t)(m0 + row) * DIM + n0 + col] = f2bf(acc[i][j][r]);
      }
}

// ---------------- V transpose ----------------
__global__ __launch_bounds__(256) void transpose_v(
    const unsigned short* __restrict__ V, unsigned short* __restrict__ VT)
{
  __shared__ unsigned short T[64][72];
  const int b  = blockIdx.z;
  const int s0 = blockIdx.x * 64;
  const int a0 = blockIdx.y * 64;
  const unsigned short* Vb = V + (size_t)b * SEQ * DIM;
  unsigned short* VTb = VT + (size_t)b * DIM * SEQ;
  const int t = threadIdx.x;
  const int r = t >> 3, cg = t & 7;
  #pragma unroll
  for (int p = 0; p < 2; ++p){
    int row = r + p * 32;
    ushortx8 v = *(const ushortx8*)(Vb + (size_t)(s0 + row) * DIM + a0 + cg*8);
    *(ushortx8*)&T[row][cg*8] = v;
  }
  __syncthreads();
  #pragma unroll
  for (int p = 0; p < 2; ++p){
    int ar = r + p * 32;
    ushortx8 o;
    #pragma unroll
    for (int j = 0; j < 8; ++j) o[j] = T[cg*8 + j][ar];
    *(ushortx8*)(VTb + (size_t)(a0 + ar) * SEQ + s0 + cg*8) = o;
  }
}

// ---------------- S/P GEMM: r15 form, triangular-packed XCD grid ----------
__global__ __launch_bounds__(256, 2) void sp_gemm(
    const unsigned short* __restrict__ Q,
    const unsigned short* __restrict__ K,
    unsigned short* __restrict__ Sp,
    float* __restrict__ lrow)
{
  const int orig = blockIdx.x;         // 0..527
  const int p    = (orig & 7) * 66 + (orig >> 3);
  const int b    = blockIdx.y;

  int ti = (int)((__builtin_sqrtf(8.0f * (float)p + 1.0f) - 1.0f) * 0.5f);
  while ((ti + 1) * (ti + 2) / 2 <= p) ++ti;
  while (ti * (ti + 1) / 2 > p) --ti;
  const int tj = p - ti * (ti + 1) / 2;

  __shared__ unsigned short As[128 * 64];
  __shared__ unsigned short Bs[128 * 64];

  const int t  = threadIdx.x;
  const int m0 = ti * 128;
  const int n0 = tj * 128;

  const int l  = t & 63;
  const int w  = t >> 6;
  const int lr = l & 15;
  const int lk = l >> 4;
  const int lk16 = lk * 16;
  const int wr = (w >> 1) * 64;
  const int wc = (w & 1) * 64;

  const char* Abase = (const char*)(Q + (size_t)b * SEQ * DIM) + (size_t)m0 * 2048;
  const char* Bbase = (const char*)(K + (size_t)b * SEQ * DIM) + (size_t)n0 * 2048;

  f32x4 acc[4][4];
  #pragma unroll
  for (int i = 0; i < 4; ++i)
    #pragma unroll
    for (int j = 0; j < 4; ++j) acc[i][j] = (f32x4)0.0f;

  for (int kt = 0; kt < DIM / 64; ++kt){
    STAGE_AB(Abase + kt * 128, 2048, Bbase + kt * 128, 2048);
    WAITVM0;
    __syncthreads();
    COMPUTE128S();
    __syncthreads();
  }

  // epilogue: P = exp(scale*acc) masked; bf16 packed write; row-sum atomics
  const float scale = 0.03125f;  // 1/sqrt(1024)
  unsigned short* tile = Sp + ((size_t)b * TRI + (size_t)p) * 16384;
  float* lb = lrow + (size_t)b * SEQ + m0;

  #pragma unroll
  for (int i = 0; i < 4; ++i){
    float rs[4] = {0.f, 0.f, 0.f, 0.f};
    #pragma unroll
    for (int j = 0; j < 4; ++j){
      #pragma unroll
      for (int r = 0; r < 4; ++r){
        int row = wr + i*16 + lk*4 + r;
        int col = wc + j*16 + lr;
        float pv = 0.0f;
        if (n0 + col <= m0 + row) pv = __expf(acc[i][j][r] * scale);
        rs[r] += pv;
        tile[row * 128 + col] = f2bf(pv);
      }
    }
    #pragma unroll
    for (int r = 0; r < 4; ++r){
      float v = rs[r];
      v += __shfl_xor(v, 1, 64);
      v += __shfl_xor(v, 2, 64);
      v += __shfl_xor(v, 4, 64);
      v += __shfl_xor(v, 8, 64);
      if (lr == 0)
        atomicAdd(&lb[wr + i*16 + lk*4 + r], v);
    }
  }
}

// ---------------- PV GEMM: r15 body, XCD-chunked (same-pr colocated) ------
__global__ __launch_bounds__(256, 2) void pv_gemm(
    const unsigned short* __restrict__ Sp,
    const unsigned short* __restrict__ VT,
    const float* __restrict__ lrow,
    float* __restrict__ out)
{
  __shared__ unsigned short As[128 * 64];
  __shared__ unsigned short Bs[128 * 64];

  const int f  = blockIdx.x;           // 0..127
  const int g  = (f & 7) * 16 + (f >> 3);
  const int pr = g >> 3;               // 0..15
  const int nx = g & 7;                // 0..7
  const int b  = blockIdx.y;
  const int t  = threadIdx.x;

  const int l  = t & 63;
  const int w  = t >> 6;
  const int lr = l & 15;
  const int lk = l >> 4;
  const int lk16 = lk * 16;
  const int wr = (w >> 1) * 64;
  const int wc = (w & 1) * 64;

  const int n0 = nx * 128;
  const char* VTb = (const char*)(VT + (size_t)b * DIM * SEQ) + (size_t)n0 * 8192;
  const unsigned short* Spb = Sp + (size_t)b * TRI * 16384;

  for (int half = 0; half < 2; ++half){
    const int ti = half ? pr : (31 - pr);
    const int m0 = ti * 128;
    const char* Pt = (const char*)(Spb + (size_t)(ti * (ti + 1) / 2) * 16384);
    const int ksteps = 2 * (ti + 1);

    f32x4 acc[4][4];
    #pragma unroll
    for (int i = 0; i < 4; ++i)
      #pragma unroll
      for (int j = 0; j < 4; ++j) acc[i][j] = (f32x4)0.0f;

    for (int s = 0; s < ksteps; ++s){
      STAGE_AB(Pt + (size_t)(s >> 1) * 32768 + (s & 1) * 128, 256,
               VTb + s * 128, 8192);
      WAITVM0;
      __syncthreads();
      COMPUTE128S();
      __syncthreads();
    }

    const float* lb = lrow + (size_t)b * SEQ + m0;
    float* ob = out + ((size_t)b * SEQ + m0) * DIM + n0;
    #pragma unroll
    for (int i = 0; i < 4; ++i)
      #pragma unroll
      for (int r = 0; r < 4; ++r){
        int row = wr + i*16 + lk*4 + r;
        float inv = 1.0f / lb[row];
        #pragma unroll
        for (int j = 0; j < 4; ++j)
          ob[(size_t)row * DIM + wc + j*16 + lr] = acc[i][j][r] * inv;
      }
  }
}

// ---------------- launch ----------------
extern "C" void kernel_launch(void* const* d_in, const int* in_sizes, int n_in,
                              void* d_out, int out_size, void* d_ws, size_t ws_size,
                              hipStream_t stream)
{
  (void)in_sizes; (void)n_in; (void)out_size; (void)ws_size;
  const float* emb = (const float*)d_in[0];
  const float* Wq  = (const float*)d_in[1];
  const float* Wk  = (const float*)d_in[2];
  const float* Wv  = (const float*)d_in[3];

  char* ws = (char*)d_ws;
  unsigned short* EB = (unsigned short*)ws;                    // 32MB (reused as VT)
  unsigned short* WB = (unsigned short*)(ws + 33554432);       // 6MB: Wq|Wk|Wv bf16
  unsigned short* Qb = (unsigned short*)(ws + 39845888);       // 32MB
  unsigned short* Kb = (unsigned short*)(ws + 73400320);       // 32MB
  unsigned short* Sp = (unsigned short*)(ws + 106954752);      // 66MB packed P tiles
  float*          lr = (float*)(ws + 176160768);               // 64KB row sums
  unsigned short* Vb = (unsigned short*)d_out;                 // V scratch in out buffer
  unsigned short* VT = EB;                                     // alias: E dead after gemm

  hipMemsetAsync(lr, 0, (size_t)NB * SEQ * sizeof(float), stream);

  cvt_all<<<19456, 256, 0, stream>>>(emb, Wq, Wk, Wv, EB, WB);

  gemm_qkv<<<768, 512, 0, stream>>>(EB, WB, Qb, Kb, Vb);
  transpose_v<<<dim3(64, 16, 4), 256, 0, stream>>>(Vb, VT);

  sp_gemm<<<dim3(528, NB), 256, 0, stream>>>(Qb, Kb, Sp, lr);
  pv_gemm<<<dim3(128, NB), 256, 0, stream>>>(Sp, VT, lr, (float*)d_out);
}